// Round 4
// baseline (815.416 us; speedup 1.0000x reference)
//
#include <hip/hip_runtime.h>
#include <stdint.h>

#define N_NODES 50000
#define M_PAD   50176   // 392*128
#define R_REL   8
#define E_EDGES 100000
#define D_IN    768
#define D_H     256
#define N_CAT   2304    // 9*256 : [self | rel0..rel7]
#define LN_EPS  1e-5f

#define TILES_M128 392
#define TILES_N128 18
#define T_TOT128   7056   // 392*18, %8==0
#define CPX128     882    // 7056/8
#define NCHUNK  49        // ceil(50000/1024)
#define EP_STRIDE 68      // epilogue repack row stride (u16): bank-conflict-free
#define E_PAD_MAX 960000  // 800k edges + <=150k pad slots

typedef __attribute__((ext_vector_type(8))) __bf16        bf16x8;
typedef __attribute__((ext_vector_type(4))) float         f32x4;
typedef __attribute__((ext_vector_type(8))) unsigned short u16x8;
typedef __attribute__((ext_vector_type(4))) unsigned short u16x4;
typedef __attribute__((ext_vector_type(4))) int            i32x4;

__device__ __forceinline__ float bf2f(unsigned short u) {
  union { float f; uint32_t i; } c; c.i = ((uint32_t)u) << 16; return c.f;
}
__device__ __forceinline__ unsigned short f2bf(float f) {
  uint32_t x = __float_as_uint(f);
  uint32_t r = (x + 0x7fffu + ((x >> 16) & 1u)) >> 16;   // RNE
  return (unsigned short)r;
}

__device__ __forceinline__ void gload_lds16(const void* g, uint32_t lds_off) {
  __builtin_amdgcn_global_load_lds(
      (const __attribute__((address_space(1))) void*)(uintptr_t)g,
      (__attribute__((address_space(3))) void*)(uintptr_t)lds_off, 16, 0, 0);
}

// ---------------- CSR build (node-major, relations flattened) ----------------
__global__ void k_deg(const int* __restrict__ tgt, int* __restrict__ deg) {
  int e = blockIdx.x * 256 + threadIdx.x;
  if (e >= R_REL * E_EDGES) return;
  int r = e / E_EDGES;
  atomicAdd(&deg[r * N_NODES + tgt[e]], 1);
}

// per-node total degree, padded to multiple of 4
__global__ void k_ndeg(const int* __restrict__ deg, int* __restrict__ pdeg) {
  int t = blockIdx.x * 256 + threadIdx.x;
  if (t >= N_NODES) return;
  int s = 0;
#pragma unroll
  for (int r = 0; r < R_REL; ++r) s += deg[r * N_NODES + t];
  pdeg[t] = (s + 3) & ~3;
}

__global__ __launch_bounds__(256)
void k_scan1(const int* __restrict__ deg, int* __restrict__ rowptr,
             int* __restrict__ bsum) {
  __shared__ int wtot[4];
  const int chunk = blockIdx.x, tid = threadIdx.x;
  const int wave = tid >> 6, lane = tid & 63;
  const int i0 = chunk * 1024 + tid * 4;
  int v0 = 0, v1 = 0, v2 = 0, v3 = 0;
  const int* d = deg;
  if (chunk != NCHUNK - 1) {
    i32x4 v = *(const i32x4*)(d + i0);
    v0 = v[0]; v1 = v[1]; v2 = v[2]; v3 = v[3];
  } else {
    if (i0 + 0 < N_NODES) v0 = d[i0 + 0];
    if (i0 + 1 < N_NODES) v1 = d[i0 + 1];
    if (i0 + 2 < N_NODES) v2 = d[i0 + 2];
    if (i0 + 3 < N_NODES) v3 = d[i0 + 3];
  }
  const int tsum = v0 + v1 + v2 + v3;
  int inc = tsum;
#pragma unroll
  for (int off = 1; off < 64; off <<= 1) {
    int t = __shfl_up(inc, off, 64);
    if (lane >= off) inc += t;
  }
  if (lane == 63) wtot[wave] = inc;
  __syncthreads();
  int woff = 0;
#pragma unroll
  for (int w = 0; w < 4; ++w) woff += (w < wave) ? wtot[w] : 0;
  int excl = woff + inc - tsum;
  int* rp = rowptr;
  if (i0 + 0 < N_NODES) rp[i0 + 0] = excl;
  if (i0 + 1 < N_NODES) rp[i0 + 1] = excl + v0;
  if (i0 + 2 < N_NODES) rp[i0 + 2] = excl + v0 + v1;
  if (i0 + 3 < N_NODES) rp[i0 + 3] = excl + v0 + v1 + v2;
  if (tid == 0) bsum[chunk] = wtot[0] + wtot[1] + wtot[2] + wtot[3];
}

__global__ __launch_bounds__(64)
void k_scan2(const int* __restrict__ bsum, int* __restrict__ chunkoff,
             int* __restrict__ rowptr) {
  const int lane = threadIdx.x & 63;
  int v = (lane < NCHUNK) ? bsum[lane] : 0;
  int inc = v;
#pragma unroll
  for (int off = 1; off < 64; off <<= 1) {
    int t = __shfl_up(inc, off, 64);
    if (lane >= off) inc += t;
  }
  if (lane < NCHUNK) chunkoff[lane] = inc - v;   // exclusive
  if (lane == NCHUNK - 1) rowptr[N_NODES] = inc;
}

__global__ __launch_bounds__(256)
void k_scan3(const int* __restrict__ chunkoff, int* __restrict__ rowptr) {
  const int chunk = blockIdx.x;
  if (chunk == 0) return;
  const int off = chunkoff[chunk];
  const int i0 = chunk * 1024 + threadIdx.x * 4;
#pragma unroll
  for (int j = 0; j < 4; ++j)
    if (i0 + j < N_NODES) rowptr[i0 + j] += off;
}

// per-node {start, padded_count}
__global__ void k_prep(const int* __restrict__ nodeptr, int2* __restrict__ scN) {
  int t = blockIdx.x * 256 + threadIdx.x;
  if (t >= N_NODES) return;
  scN[t] = make_int2(nodeptr[t], nodeptr[t + 1] - nodeptr[t]);
}

// fill flattened adjacency: e2[slot] = {src | rel<<16, nw[src]/deg[rel][tgt]}
__global__ void k_fill(const int* __restrict__ src, const int* __restrict__ tgt,
                       const float* __restrict__ nw, const int* __restrict__ nodeptr,
                       const int* __restrict__ deg, int* __restrict__ cursor,
                       int2* __restrict__ e2) {
  int e = blockIdx.x * 256 + threadIdx.x;
  if (e >= R_REL * E_EDGES) return;
  int r = e / E_EDGES;
  int t = tgt[e], s = src[e];
  int pos = atomicAdd(&cursor[t], 1);
  int slot = nodeptr[t] + pos;
  float w = nw[s] / (float)deg[r * N_NODES + t];
  e2[slot] = make_int2(s | (r << 16), __float_as_int(w));
}

// ---------------- conversions ----------------
__global__ void k_cvt_x(const float* __restrict__ x, unsigned short* __restrict__ xb) {
  const size_t i = ((size_t)blockIdx.x * 256 + threadIdx.x) * 4;
  if (i >= (size_t)N_NODES * D_IN) return;
  const f32x4 v = *(const f32x4*)(x + i);
  u16x4 o = { f2bf(v[0]), f2bf(v[1]), f2bf(v[2]), f2bf(v[3]) };
  *(u16x4*)(xb + i) = o;
}

// Wt[n][k] = n<256 ? Wself[k][n] : Wrel[(n-256)>>8][k][n&255]   (bf16, [N_CAT][K])
__global__ void k_cvt_w(const float* __restrict__ Ws, const float* __restrict__ Wr,
                        unsigned short* __restrict__ Wt, int K) {
  int idx = blockIdx.x * 256 + threadIdx.x;
  if (idx >= N_CAT * K) return;
  int n = idx / K, k = idx - n * K;
  float v = (n < 256) ? Ws[k * 256 + n]
                      : Wr[(size_t)((n - 256) >> 8) * K * 256 + k * 256 + (n & 255)];
  Wt[idx] = f2bf(v);
}

// ---------------- bf16 MFMA GEMM, 128x128 tile, BK=32 dbuf, 4 blocks/CU ----------------
// C[M_PAD,N_CAT] = A @ Bt^T. 4 waves (2M x 2N), per-wave 64x64 output (acc[4][4]=64 regs).
// Occupancy is the lever (r3 lesson): 64x64/wave keeps combined regs ~120 ->
// __launch_bounds__(256,4) targets 4 waves/SIMD = 4 blocks/CU = 16 waves/CU; cross-
// block TLP hides barrier/lgkm/vmcnt stalls (what made the r0 kernel fast at 12 waves).
// LDS: bufA[2][128 rows][64 B] @0 (16 KiB), bufB[2] @16384 (16 KiB); epilogue 34816.
// Row = 64 B = 4 x 16B chunks; chunk c of row r at slot c ^ ((r>>1)&3): staging is
// linear dest + pre-swizzled global src; fragment ds_read_b128 is conflict-free per
// 8-lane beat (granules {0,4,1,5,2,6,3,7}).
// Per BK=32 tile: stage next tile (4 gloads) -> read 8 b128 -> 16 MFMA -> vmcnt(0)+bar.
__global__ __launch_bounds__(256, 4)
void k_gemm(const unsigned short* __restrict__ A, const unsigned short* __restrict__ Bt,
            unsigned short* __restrict__ C, int K) {
  __shared__ __align__(16) char smem[34816];

  // XCD swizzle (7056 % 8 == 0 -> simple bijective chunked form)
  const int bid = blockIdx.x;
  const int wg = (bid & 7) * CPX128 + (bid >> 3);
  const int tileM = (wg / TILES_N128) * 128;
  const int tileN = (wg % TILES_N128) * 128;

  const int tid = threadIdx.x, wave = tid >> 6, lane = tid & 63;
  const int wm = (wave >> 1) * 64, wn = (wave & 1) * 64;
  const int c16 = lane & 15, fph = lane >> 4;

  // staging: gload j covers 64 rows (4 KiB); srow = j*64 + (tid>>2), slot = tid&3
  const int srow = tid >> 2;
  const int cch = (tid & 3) ^ ((srow >> 1) & 3);     // pre-swizzled global chunk
  const unsigned short* gAr0 = A  + (size_t)(tileM + srow) * K + cch * 8;
  const unsigned short* gAr1 = gAr0 + (size_t)64 * K;
  const unsigned short* gBr0 = Bt + (size_t)(tileN + srow) * K + cch * 8;
  const unsigned short* gBr1 = gBr0 + (size_t)64 * K;
  const uint32_t ldsA = (uint32_t)(uintptr_t)smem;
  const uint32_t ldsB = ldsA + 16384u;
  const uint32_t lin = (uint32_t)(tid * 16);

  f32x4 acc[4][4] = {};

  // fragment bases: row stride 64 B; slot = (fph ^ ((c16>>1)&3))*16, invariant in mi
  const int slot = (fph ^ ((c16 >> 1) & 3)) * 16;
  const char* pA = smem         + (wm + c16) * 64 + slot;
  const char* pB = smem + 16384 + (wn + c16) * 64 + slot;

  const int nk = K >> 5;                              // 24 (K=768) or 8 (K=256)

  // prologue: tile0 -> parity 0
  gload_lds16(gAr0, ldsA + lin);
  gload_lds16(gAr1, ldsA + 4096u + lin);
  gload_lds16(gBr0, ldsB + lin);
  gload_lds16(gBr1, ldsB + 4096u + lin);
  asm volatile("s_waitcnt vmcnt(0)" ::: "memory");
  asm volatile("s_barrier" ::: "memory");

  for (int tp = 0; tp < nk; tp += 2) {
#pragma unroll
    for (int u = 0; u < 2; ++u) {
      const uint32_t par  = u ? 8192u : 0u;           // buffer of tile tp+u
      const uint32_t parN = u ? 0u : 8192u;           // buffer of tile tp+u+1
      const int t = tp + u;
      // stage t+1 into other parity (that buffer's data was consumed before the
      // previous trailing barrier; in-flight count after issue = exactly these 4)
      if (t + 1 < nk) {
        const int soff = (u + 1) * 32;
        gload_lds16(gAr0 + soff, ldsA + parN + lin);
        gload_lds16(gAr1 + soff, ldsA + parN + 4096u + lin);
        gload_lds16(gBr0 + soff, ldsB + parN + lin);
        gload_lds16(gBr1 + soff, ldsB + parN + 4096u + lin);
      }
      bf16x8 bfr[4], af[4];
#pragma unroll
      for (int nj = 0; nj < 4; ++nj) bfr[nj] = *(const bf16x8*)(pB + par + nj * 1024);
#pragma unroll
      for (int mi = 0; mi < 4; ++mi) af[mi]  = *(const bf16x8*)(pA + par + mi * 1024);
#pragma unroll
      for (int mi = 0; mi < 4; ++mi)
#pragma unroll
        for (int nj = 0; nj < 4; ++nj)
          acc[mi][nj] = __builtin_amdgcn_mfma_f32_16x16x32_bf16(af[mi], bfr[nj],
                                                                acc[mi][nj], 0, 0, 0);
      if (t + 1 < nk) {
        asm volatile("s_waitcnt vmcnt(0)" ::: "memory");  // t+1 landed (only its 4 in flight)
        asm volatile("s_barrier" ::: "memory");           // + all waves done reading par
      }
    }
    gAr0 += 64; gAr1 += 64; gBr0 += 64; gBr1 += 64;
  }
  asm volatile("s_barrier" ::: "memory");             // GEMM LDS dead -> epilogue reuse

  // epilogue: AGPR -> LDS (bf16, stride-68 u16) -> 16B global stores (r0-verified)
  unsigned short* st = (unsigned short*)smem + wave * (64 * EP_STRIDE);
  const int rq4 = (lane >> 4) * 4, cq = lane & 15;
#pragma unroll
  for (int i = 0; i < 4; ++i)
#pragma unroll
    for (int j = 0; j < 4; ++j)
#pragma unroll
      for (int p = 0; p < 4; ++p)
        st[(i * 16 + rq4 + p) * EP_STRIDE + j * 16 + cq] = f2bf(acc[i][j][p]);
#pragma unroll
  for (int pass = 0; pass < 8; ++pass) {
    const int row = pass * 8 + (lane >> 3);
    const unsigned short* rp_ = st + row * EP_STRIDE + (lane & 7) * 8;
    u16x4 lo = *(const u16x4*)(rp_);
    u16x4 hi = *(const u16x4*)(rp_ + 4);
    u16x8 v = { lo[0], lo[1], lo[2], lo[3], hi[0], hi[1], hi[2], hi[3] };
    size_t off = (size_t)(tileM + wm + row) * N_CAT + tileN + wn + (lane & 7) * 8;
    *(u16x8*)(C + off) = v;
  }
}

// ---------------- fused gather + mean + self + bias + ReLU + LayerNorm ----------------
// one wave per node, 4 channels/lane; single flattened edge loop, 4 edges in flight.
template <int FINAL>
__global__ __launch_bounds__(256)
void k_gather_ln(const unsigned short* __restrict__ Y, const int2* __restrict__ scN,
                 const int2* __restrict__ e2, const float* __restrict__ bias,
                 const float* __restrict__ g, const float* __restrict__ bln,
                 void* __restrict__ out) {
  const int wave = threadIdx.x >> 6, lane = threadIdx.x & 63;
  const int t = blockIdx.x * 4 + wave;
  if (t >= N_NODES) return;
  const int c0 = lane * 4;

  float a0, a1, a2, a3;
  {
    u16x4 sv = *(const u16x4*)(Y + (size_t)t * N_CAT + c0);
    f32x4 bb = *(const f32x4*)(bias + c0);
    a0 = bf2f(sv[0]) + bb[0];
    a1 = bf2f(sv[1]) + bb[1];
    a2 = bf2f(sv[2]) + bb[2];
    a3 = bf2f(sv[3]) + bb[3];
  }

  const int2 s = scN[t];                    // {start, padded_cnt (x4)}
  const int2* ep = e2 + s.x;
  for (int idx = 0; idx < s.y; idx += 4) {
    const int2 p0 = ep[idx + 0];
    const int2 p1 = ep[idx + 1];
    const int2 p2 = ep[idx + 2];
    const int2 p3 = ep[idx + 3];
    // addr: Y + src*2304 + (rel+1)*256 + c0 ; pad slots are {0,w=0} -> add 0
    const unsigned short* y0 = Y + (size_t)(p0.x & 0xFFFF) * N_CAT + (((p0.x >> 16) + 1) << 8) + c0;
    const unsigned short* y1 = Y + (size_t)(p1.x & 0xFFFF) * N_CAT + (((p1.x >> 16) + 1) << 8) + c0;
    const unsigned short* y2 = Y + (size_t)(p2.x & 0xFFFF) * N_CAT + (((p2.x >> 16) + 1) << 8) + c0;
    const unsigned short* y3 = Y + (size_t)(p3.x & 0xFFFF) * N_CAT + (((p3.x >> 16) + 1) << 8) + c0;
    u16x4 v0 = *(const u16x4*)y0;
    u16x4 v1 = *(const u16x4*)y1;
    u16x4 v2 = *(const u16x4*)y2;
    u16x4 v3 = *(const u16x4*)y3;
    const float w0 = __int_as_float(p0.y), w1 = __int_as_float(p1.y);
    const float w2 = __int_as_float(p2.y), w3 = __int_as_float(p3.y);
    a0 += w0 * bf2f(v0[0]) + w1 * bf2f(v1[0]) + w2 * bf2f(v2[0]) + w3 * bf2f(v3[0]);
    a1 += w0 * bf2f(v0[1]) + w1 * bf2f(v1[1]) + w2 * bf2f(v2[1]) + w3 * bf2f(v3[1]);
    a2 += w0 * bf2f(v0[2]) + w1 * bf2f(v1[2]) + w2 * bf2f(v2[2]) + w3 * bf2f(v3[2]);
    a3 += w0 * bf2f(v0[3]) + w1 * bf2f(v1[3]) + w2 * bf2f(v2[3]) + w3 * bf2f(v3[3]);
  }

  a0 = fmaxf(a0, 0.f); a1 = fmaxf(a1, 0.f); a2 = fmaxf(a2, 0.f); a3 = fmaxf(a3, 0.f);

  float s1 = (a0 + a1) + (a2 + a3);
#pragma unroll
  for (int off = 32; off > 0; off >>= 1) s1 += __shfl_xor(s1, off, 64);
  const float mu = s1 * (1.f / 256.f);
  const float d0 = a0 - mu, d1 = a1 - mu, d2 = a2 - mu, d3 = a3 - mu;
  float s2 = (d0 * d0 + d1 * d1) + (d2 * d2 + d3 * d3);
#pragma unroll
  for (int off = 32; off > 0; off >>= 1) s2 += __shfl_xor(s2, off, 64);
  const float rs = rsqrtf(s2 * (1.f / 256.f) + LN_EPS);

  f32x4 gg = *(const f32x4*)(g + c0);
  f32x4 ll = *(const f32x4*)(bln + c0);
  const float o0 = d0 * rs * gg[0] + ll[0];
  const float o1 = d1 * rs * gg[1] + ll[1];
  const float o2 = d2 * rs * gg[2] + ll[2];
  const float o3 = d3 * rs * gg[3] + ll[3];
  if (FINAL) {
    f32x4 o = { o0, o1, o2, o3 };
    *(f32x4*)((float*)out + (size_t)t * 256 + c0) = o;
  } else {
    u16x4 o = { f2bf(o0), f2bf(o1), f2bf(o2), f2bf(o3) };
    *(u16x4*)((unsigned short*)out + (size_t)t * 256 + c0) = o;
  }
}

// ---------------- launch ----------------
extern "C" void kernel_launch(void* const* d_in, const int* in_sizes, int n_in,
                              void* d_out, int out_size, void* d_ws, size_t ws_size,
                              hipStream_t stream) {
  (void)in_sizes; (void)n_in; (void)out_size; (void)ws_size;
  const float* x   = (const float*)d_in[0];
  const float* nw  = (const float*)d_in[1];
  const int*   esrc = (const int*)d_in[2];
  const int*   etgt = (const int*)d_in[3];
  const float* Wr0 = (const float*)d_in[4];
  const float* Ws0 = (const float*)d_in[5];
  const float* Wb0 = (const float*)d_in[6];
  const float* g0  = (const float*)d_in[7];
  const float* b0  = (const float*)d_in[8];
  const float* Wr1 = (const float*)d_in[9];
  const float* Ws1 = (const float*)d_in[10];
  const float* Wb1 = (const float*)d_in[11];
  const float* g1  = (const float*)d_in[12];
  const float* b1  = (const float*)d_in[13];

  char* p = (char*)d_ws;
  auto carve = [&](size_t bytes) {
    char* q = p;
    p += (bytes + 511) & ~(size_t)511;
    return q;
  };
  unsigned short* Y   = (unsigned short*)carve((size_t)M_PAD * N_CAT * 2);  // 231.2 MB
  unsigned short* xb  = (unsigned short*)carve((size_t)M_PAD * D_IN * 2);   //  77.1 MB
  unsigned short* h   = (unsigned short*)carve((size_t)M_PAD * D_H * 2);    //  25.7 MB
  unsigned short* Wt0 = (unsigned short*)carve((size_t)N_CAT * D_IN * 2);
  unsigned short* Wt1 = (unsigned short*)carve((size_t)N_CAT * D_H * 2);
  int*   deg     = (int*)carve((size_t)R_REL * N_NODES * 4);
  int*   pdeg    = (int*)carve((size_t)N_NODES * 4);
  int*   cursor  = (int*)carve((size_t)N_NODES * 4);
  int*   nodeptr = (int*)carve((size_t)(N_NODES + 1) * 4);
  int*   bsum    = (int*)carve((size_t)NCHUNK * 4);
  int*   chunkoff= (int*)carve((size_t)NCHUNK * 4);
  int2*  e2      = (int2*)carve((size_t)E_PAD_MAX * 8);
  int2*  scN     = (int2*)carve((size_t)N_NODES * 8);

  // CSR build (node-major; shared by both layers)
  hipMemsetAsync(deg, 0, (size_t)R_REL * N_NODES * 4, stream);
  hipMemsetAsync(cursor, 0, (size_t)N_NODES * 4, stream);
  hipMemsetAsync(e2, 0, (size_t)E_PAD_MAX * 8, stream);   // pad slots -> {src0, w=0}
  k_deg<<<(R_REL * E_EDGES + 255) / 256, 256, 0, stream>>>(etgt, deg);
  k_ndeg<<<(N_NODES + 255) / 256, 256, 0, stream>>>(deg, pdeg);
  k_scan1<<<NCHUNK, 256, 0, stream>>>(pdeg, nodeptr, bsum);
  k_scan2<<<1, 64, 0, stream>>>(bsum, chunkoff, nodeptr);
  k_scan3<<<NCHUNK, 256, 0, stream>>>(chunkoff, nodeptr);
  k_prep<<<(N_NODES + 255) / 256, 256, 0, stream>>>(nodeptr, scN);
  k_fill<<<(R_REL * E_EDGES + 255) / 256, 256, 0, stream>>>(esrc, etgt, nw, nodeptr,
                                                            deg, cursor, e2);
  // conversions
  k_cvt_x<<<(N_NODES * D_IN / 4 + 255) / 256, 256, 0, stream>>>(x, xb);
  k_cvt_w<<<(N_CAT * D_IN + 255) / 256, 256, 0, stream>>>(Ws0, Wr0, Wt0, D_IN);
  k_cvt_w<<<(N_CAT * D_H + 255) / 256, 256, 0, stream>>>(Ws1, Wr1, Wt1, D_H);

  // layer 0
  k_gemm<<<T_TOT128, 256, 0, stream>>>(xb, Wt0, Y, D_IN);
  k_gather_ln<0><<<N_NODES / 4, 256, 0, stream>>>(Y, scN, e2, Wb0, g0, b0, h);
  // layer 1
  k_gemm<<<T_TOT128, 256, 0, stream>>>(h, Wt1, Y, D_H);
  k_gather_ln<1><<<N_NODES / 4, 256, 0, stream>>>(Y, scN, e2, Wb1, g1, b1, d_out);
}

// Round 5
// 800.356 us; speedup vs baseline: 1.0188x; 1.0188x over previous
//
#include <hip/hip_runtime.h>
#include <stdint.h>

#define N_NODES 50000
#define M_PAD   50048   // 391*128
#define R_REL   8
#define E_EDGES 100000
#define D_IN    768
#define D_H     256
#define N_CAT   2304    // 9*256 : [self | rel0..rel7]
#define LN_EPS  1e-5f

#define TILES_N 18      // N_CAT/128
#define TILES_M 391     // M_PAD/128
#define T_TOT   (TILES_N * TILES_M)          // 7038
#define T_PER_XCD ((T_TOT + 7) / 8)          // 880
#define NCHUNK  49      // ceil(50000/1024)
#define EP_STRIDE 68    // epilogue repack row stride (u16): bank-conflict-free
#define E_PAD_MAX 1200000 // 800k edges + <=350k pad slots (deg padded to x8)

typedef __attribute__((ext_vector_type(8))) __bf16        bf16x8;
typedef __attribute__((ext_vector_type(4))) float         f32x4;
typedef __attribute__((ext_vector_type(8))) unsigned short u16x8;
typedef __attribute__((ext_vector_type(4))) unsigned short u16x4;
typedef __attribute__((ext_vector_type(4))) int            i32x4;

__device__ __forceinline__ float bf2f(unsigned short u) {
  union { float f; uint32_t i; } c; c.i = ((uint32_t)u) << 16; return c.f;
}
__device__ __forceinline__ unsigned short f2bf(float f) {
  uint32_t x = __float_as_uint(f);
  uint32_t r = (x + 0x7fffu + ((x >> 16) & 1u)) >> 16;   // RNE
  return (unsigned short)r;
}

__device__ __forceinline__ void gload_lds16(const void* g, uint32_t lds_off) {
  __builtin_amdgcn_global_load_lds(
      (const __attribute__((address_space(1))) void*)(uintptr_t)g,
      (__attribute__((address_space(3))) void*)(uintptr_t)lds_off, 16, 0, 0);
}

// ---------------- CSR build (node-major, relations flattened) ----------------
__global__ void k_deg(const int* __restrict__ tgt, int* __restrict__ deg) {
  int e = blockIdx.x * 256 + threadIdx.x;
  if (e >= R_REL * E_EDGES) return;
  int r = e / E_EDGES;
  atomicAdd(&deg[r * N_NODES + tgt[e]], 1);
}

// per-node total degree, padded to multiple of 8 (gather runs 8 edges in flight)
__global__ void k_ndeg(const int* __restrict__ deg, int* __restrict__ pdeg) {
  int t = blockIdx.x * 256 + threadIdx.x;
  if (t >= N_NODES) return;
  int s = 0;
#pragma unroll
  for (int r = 0; r < R_REL; ++r) s += deg[r * N_NODES + t];
  pdeg[t] = (s + 7) & ~7;
}

__global__ __launch_bounds__(256)
void k_scan1(const int* __restrict__ deg, int* __restrict__ rowptr,
             int* __restrict__ bsum) {
  __shared__ int wtot[4];
  const int chunk = blockIdx.x, tid = threadIdx.x;
  const int wave = tid >> 6, lane = tid & 63;
  const int i0 = chunk * 1024 + tid * 4;
  int v0 = 0, v1 = 0, v2 = 0, v3 = 0;
  const int* d = deg;
  if (chunk != NCHUNK - 1) {
    i32x4 v = *(const i32x4*)(d + i0);
    v0 = v[0]; v1 = v[1]; v2 = v[2]; v3 = v[3];
  } else {
    if (i0 + 0 < N_NODES) v0 = d[i0 + 0];
    if (i0 + 1 < N_NODES) v1 = d[i0 + 1];
    if (i0 + 2 < N_NODES) v2 = d[i0 + 2];
    if (i0 + 3 < N_NODES) v3 = d[i0 + 3];
  }
  const int tsum = v0 + v1 + v2 + v3;
  int inc = tsum;
#pragma unroll
  for (int off = 1; off < 64; off <<= 1) {
    int t = __shfl_up(inc, off, 64);
    if (lane >= off) inc += t;
  }
  if (lane == 63) wtot[wave] = inc;
  __syncthreads();
  int woff = 0;
#pragma unroll
  for (int w = 0; w < 4; ++w) woff += (w < wave) ? wtot[w] : 0;
  int excl = woff + inc - tsum;
  int* rp = rowptr;
  if (i0 + 0 < N_NODES) rp[i0 + 0] = excl;
  if (i0 + 1 < N_NODES) rp[i0 + 1] = excl + v0;
  if (i0 + 2 < N_NODES) rp[i0 + 2] = excl + v0 + v1;
  if (i0 + 3 < N_NODES) rp[i0 + 3] = excl + v0 + v1 + v2;
  if (tid == 0) bsum[chunk] = wtot[0] + wtot[1] + wtot[2] + wtot[3];
}

__global__ __launch_bounds__(64)
void k_scan2(const int* __restrict__ bsum, int* __restrict__ chunkoff,
             int* __restrict__ rowptr) {
  const int lane = threadIdx.x & 63;
  int v = (lane < NCHUNK) ? bsum[lane] : 0;
  int inc = v;
#pragma unroll
  for (int off = 1; off < 64; off <<= 1) {
    int t = __shfl_up(inc, off, 64);
    if (lane >= off) inc += t;
  }
  if (lane < NCHUNK) chunkoff[lane] = inc - v;   // exclusive
  if (lane == NCHUNK - 1) rowptr[N_NODES] = inc;
}

__global__ __launch_bounds__(256)
void k_scan3(const int* __restrict__ chunkoff, int* __restrict__ rowptr) {
  const int chunk = blockIdx.x;
  if (chunk == 0) return;
  const int off = chunkoff[chunk];
  const int i0 = chunk * 1024 + threadIdx.x * 4;
#pragma unroll
  for (int j = 0; j < 4; ++j)
    if (i0 + j < N_NODES) rowptr[i0 + j] += off;
}

// per-node {start, padded_count}
__global__ void k_prep(const int* __restrict__ nodeptr, int2* __restrict__ scN) {
  int t = blockIdx.x * 256 + threadIdx.x;
  if (t >= N_NODES) return;
  scN[t] = make_int2(nodeptr[t], nodeptr[t + 1] - nodeptr[t]);
}

// fill flattened adjacency: e2[slot] = {src | rel<<16, nw[src]/deg[rel][tgt]}
__global__ void k_fill(const int* __restrict__ src, const int* __restrict__ tgt,
                       const float* __restrict__ nw, const int* __restrict__ nodeptr,
                       const int* __restrict__ deg, int* __restrict__ cursor,
                       int2* __restrict__ e2) {
  int e = blockIdx.x * 256 + threadIdx.x;
  if (e >= R_REL * E_EDGES) return;
  int r = e / E_EDGES;
  int t = tgt[e], s = src[e];
  int pos = atomicAdd(&cursor[t], 1);
  int slot = nodeptr[t] + pos;
  float w = nw[s] / (float)deg[r * N_NODES + t];
  e2[slot] = make_int2(s | (r << 16), __float_as_int(w));
}

// ---------------- conversions ----------------
__global__ void k_cvt_x(const float* __restrict__ x, unsigned short* __restrict__ xb) {
  const size_t i = ((size_t)blockIdx.x * 256 + threadIdx.x) * 4;
  if (i >= (size_t)N_NODES * D_IN) return;
  const f32x4 v = *(const f32x4*)(x + i);
  u16x4 o = { f2bf(v[0]), f2bf(v[1]), f2bf(v[2]), f2bf(v[3]) };
  *(u16x4*)(xb + i) = o;
}

// Wt[n][k] = n<256 ? Wself[k][n] : Wrel[(n-256)>>8][k][n&255]   (bf16, [N_CAT][K])
__global__ void k_cvt_w(const float* __restrict__ Ws, const float* __restrict__ Wr,
                        unsigned short* __restrict__ Wt, int K) {
  int idx = blockIdx.x * 256 + threadIdx.x;
  if (idx >= N_CAT * K) return;
  int n = idx / K, k = idx - n * K;
  float v = (n < 256) ? Ws[k * 256 + n]
                      : Wr[(size_t)((n - 256) >> 8) * K * 256 + k * 256 + (n & 255)];
  Wt[idx] = f2bf(v);
}

// ---------------- bf16 MFMA GEMM, BK=64: C[M_PAD,N_CAT] = A @ Bt^T ----------------
// r0-verified structure (202 us, 877 TF = the m97-structure ceiling; r1-r4 schedule
// variants all landed 850-880 TF -> keep this one). Single change vs r0: nontemporal
// C stores (C has zero reuse in-kernel; the 225 MB stream was thrashing L2 and
// inflating A re-fetch to 254 MB).
// LDS rows are 128 B (8 x 16B chunks); slot s of row r holds chunk s^(r&7) -> both
// staging (wave-uniform base + lane*16) and fragment reads are conflict-free.
__global__ __launch_bounds__(256, 2)
void k_gemm(const unsigned short* __restrict__ A, const unsigned short* __restrict__ Bt,
            unsigned short* __restrict__ C, int K) {
  const int tile = (blockIdx.x & 7) * T_PER_XCD + (blockIdx.x >> 3);
  if (tile >= T_TOT) return;
  const int tileM = (tile / TILES_N) * 128;
  const int tileN = (tile % TILES_N) * 128;

  __shared__ __align__(16) char smem[34816];   // A 16K @0, B 16K @16384; epilogue 34816
  const int tid  = threadIdx.x;
  const int wave = tid >> 6, lane = tid & 63;
  const int wm = (wave >> 1) * 64, wn = (wave & 1) * 64;

  f32x4 acc[4][4] = {};

  // staging: call j covers rows j*32..j*32+31; wave w rows w*8+(l>>3); slot l&7
  const int rl = lane >> 3, sl8 = lane & 7;
  const int cch = sl8 ^ rl;                      // global chunk fetched by this lane
  const int srow = wave * 8 + rl;
  const unsigned short* gA = A  + (size_t)(tileM + srow) * K + cch * 8;
  const unsigned short* gB = Bt + (size_t)(tileN + srow) * K + cch * 8;
  const uint32_t ldsA = (uint32_t)(uintptr_t)smem;
  const uint32_t ldsB = ldsA + 16384;
  const uint32_t lA0 = ldsA + (wave * 8) * 128;
  const uint32_t lB0 = ldsB + (wave * 8) * 128;

  // fragment read bases: row stride 128B; chunk c=kk*4+p at slot c^(lane&7)
  const char* pAb = smem         + (wm + (lane & 15)) * 128;
  const char* pBb = smem + 16384 + (wn + (lane & 15)) * 128;
  const int fph = lane >> 4, x7 = lane & 7;

  const int nk = K >> 6;
  for (int kt = 0; kt < nk; ++kt) {
    const size_t koff = (size_t)kt * 64;
    __syncthreads();
#pragma unroll
    for (int j = 0; j < 4; ++j) {
      gload_lds16(gA + (size_t)j * 32 * K + koff, lA0 + j * 4096);
      gload_lds16(gB + (size_t)j * 32 * K + koff, lB0 + j * 4096);
    }
    __syncthreads();
#pragma unroll
    for (int kk = 0; kk < 2; ++kk) {
      const int sA = ((kk * 4 + fph) ^ x7) * 16;
      bf16x8 af[4], bfr[4];
#pragma unroll
      for (int i = 0; i < 4; ++i) af[i]  = *(const bf16x8*)(pAb + i * 2048 + sA);
#pragma unroll
      for (int j = 0; j < 4; ++j) bfr[j] = *(const bf16x8*)(pBb + j * 2048 + sA);
#pragma unroll
      for (int i = 0; i < 4; ++i)
#pragma unroll
        for (int j = 0; j < 4; ++j)
          acc[i][j] = __builtin_amdgcn_mfma_f32_16x16x32_bf16(af[i], bfr[j], acc[i][j], 0, 0, 0);
    }
  }

  // epilogue: AGPR -> LDS (bf16, stride-68 u16) -> 16B nontemporal global stores
  __syncthreads();
  unsigned short* st = (unsigned short*)smem + wave * (64 * EP_STRIDE);
  const int rq = (lane >> 4) * 4, cq = lane & 15;
#pragma unroll
  for (int i = 0; i < 4; ++i)
#pragma unroll
    for (int j = 0; j < 4; ++j)
#pragma unroll
      for (int p = 0; p < 4; ++p)
        st[(i * 16 + rq + p) * EP_STRIDE + j * 16 + cq] = f2bf(acc[i][j][p]);
#pragma unroll
  for (int pass = 0; pass < 8; ++pass) {
    const int row = pass * 8 + (lane >> 3);
    const unsigned short* rp_ = st + row * EP_STRIDE + (lane & 7) * 8;
    u16x4 lo = *(const u16x4*)(rp_);
    u16x4 hi = *(const u16x4*)(rp_ + 4);
    u16x8 v = { lo[0], lo[1], lo[2], lo[3], hi[0], hi[1], hi[2], hi[3] };
    size_t off = (size_t)(tileM + wm + row) * N_CAT + tileN + wn + (lane & 7) * 8;
    __builtin_nontemporal_store(v, (u16x8*)(C + off));
  }
}

// ---------------- fused gather + mean + self + bias + ReLU + LayerNorm ----------------
// one wave per node, 4 channels/lane; flattened edge loop, EIGHT edges in flight
// (r4 analysis: 4-deep left the wave stalled on the descriptor->gather->FMA chain;
// degree is padded to x8 so the loop needs no tail).
template <int FINAL>
__global__ __launch_bounds__(256)
void k_gather_ln(const unsigned short* __restrict__ Y, const int2* __restrict__ scN,
                 const int2* __restrict__ e2, const float* __restrict__ bias,
                 const float* __restrict__ g, const float* __restrict__ bln,
                 void* __restrict__ out) {
  const int wave = threadIdx.x >> 6, lane = threadIdx.x & 63;
  const int t = blockIdx.x * 4 + wave;
  if (t >= N_NODES) return;
  const int c0 = lane * 4;

  float a0, a1, a2, a3;
  {
    u16x4 sv = *(const u16x4*)(Y + (size_t)t * N_CAT + c0);
    f32x4 bb = *(const f32x4*)(bias + c0);
    a0 = bf2f(sv[0]) + bb[0];
    a1 = bf2f(sv[1]) + bb[1];
    a2 = bf2f(sv[2]) + bb[2];
    a3 = bf2f(sv[3]) + bb[3];
  }

  const int2 s = scN[t];                    // {start, padded_cnt (x8)}
  const int2* ep = e2 + s.x;
  for (int idx = 0; idx < s.y; idx += 8) {
    const int2 p0 = ep[idx + 0];
    const int2 p1 = ep[idx + 1];
    const int2 p2 = ep[idx + 2];
    const int2 p3 = ep[idx + 3];
    const int2 p4 = ep[idx + 4];
    const int2 p5 = ep[idx + 5];
    const int2 p6 = ep[idx + 6];
    const int2 p7 = ep[idx + 7];
    // addr: Y + src*2304 + (rel+1)*256 + c0 ; pad slots are {0,w=0} -> add 0
    const unsigned short* y0 = Y + (size_t)(p0.x & 0xFFFF) * N_CAT + (((p0.x >> 16) + 1) << 8) + c0;
    const unsigned short* y1 = Y + (size_t)(p1.x & 0xFFFF) * N_CAT + (((p1.x >> 16) + 1) << 8) + c0;
    const unsigned short* y2 = Y + (size_t)(p2.x & 0xFFFF) * N_CAT + (((p2.x >> 16) + 1) << 8) + c0;
    const unsigned short* y3 = Y + (size_t)(p3.x & 0xFFFF) * N_CAT + (((p3.x >> 16) + 1) << 8) + c0;
    const unsigned short* y4 = Y + (size_t)(p4.x & 0xFFFF) * N_CAT + (((p4.x >> 16) + 1) << 8) + c0;
    const unsigned short* y5 = Y + (size_t)(p5.x & 0xFFFF) * N_CAT + (((p5.x >> 16) + 1) << 8) + c0;
    const unsigned short* y6 = Y + (size_t)(p6.x & 0xFFFF) * N_CAT + (((p6.x >> 16) + 1) << 8) + c0;
    const unsigned short* y7 = Y + (size_t)(p7.x & 0xFFFF) * N_CAT + (((p7.x >> 16) + 1) << 8) + c0;
    u16x4 v0 = *(const u16x4*)y0;
    u16x4 v1 = *(const u16x4*)y1;
    u16x4 v2 = *(const u16x4*)y2;
    u16x4 v3 = *(const u16x4*)y3;
    u16x4 v4 = *(const u16x4*)y4;
    u16x4 v5 = *(const u16x4*)y5;
    u16x4 v6 = *(const u16x4*)y6;
    u16x4 v7 = *(const u16x4*)y7;
    const float w0 = __int_as_float(p0.y), w1 = __int_as_float(p1.y);
    const float w2 = __int_as_float(p2.y), w3 = __int_as_float(p3.y);
    const float w4 = __int_as_float(p4.y), w5 = __int_as_float(p5.y);
    const float w6 = __int_as_float(p6.y), w7 = __int_as_float(p7.y);
    a0 += w0 * bf2f(v0[0]) + w1 * bf2f(v1[0]) + w2 * bf2f(v2[0]) + w3 * bf2f(v3[0])
        + w4 * bf2f(v4[0]) + w5 * bf2f(v5[0]) + w6 * bf2f(v6[0]) + w7 * bf2f(v7[0]);
    a1 += w0 * bf2f(v0[1]) + w1 * bf2f(v1[1]) + w2 * bf2f(v2[1]) + w3 * bf2f(v3[1])
        + w4 * bf2f(v4[1]) + w5 * bf2f(v5[1]) + w6 * bf2f(v6[1]) + w7 * bf2f(v7[1]);
    a2 += w0 * bf2f(v0[2]) + w1 * bf2f(v1[2]) + w2 * bf2f(v2[2]) + w3 * bf2f(v3[2])
        + w4 * bf2f(v4[2]) + w5 * bf2f(v5[2]) + w6 * bf2f(v6[2]) + w7 * bf2f(v7[2]);
    a3 += w0 * bf2f(v0[3]) + w1 * bf2f(v1[3]) + w2 * bf2f(v2[3]) + w3 * bf2f(v3[3])
        + w4 * bf2f(v4[3]) + w5 * bf2f(v5[3]) + w6 * bf2f(v6[3]) + w7 * bf2f(v7[3]);
  }

  a0 = fmaxf(a0, 0.f); a1 = fmaxf(a1, 0.f); a2 = fmaxf(a2, 0.f); a3 = fmaxf(a3, 0.f);

  float s1 = (a0 + a1) + (a2 + a3);
#pragma unroll
  for (int off = 32; off > 0; off >>= 1) s1 += __shfl_xor(s1, off, 64);
  const float mu = s1 * (1.f / 256.f);
  const float d0 = a0 - mu, d1 = a1 - mu, d2 = a2 - mu, d3 = a3 - mu;
  float s2 = (d0 * d0 + d1 * d1) + (d2 * d2 + d3 * d3);
#pragma unroll
  for (int off = 32; off > 0; off >>= 1) s2 += __shfl_xor(s2, off, 64);
  const float rs = rsqrtf(s2 * (1.f / 256.f) + LN_EPS);

  f32x4 gg = *(const f32x4*)(g + c0);
  f32x4 ll = *(const f32x4*)(bln + c0);
  const float o0 = d0 * rs * gg[0] + ll[0];
  const float o1 = d1 * rs * gg[1] + ll[1];
  const float o2 = d2 * rs * gg[2] + ll[2];
  const float o3 = d3 * rs * gg[3] + ll[3];
  if (FINAL) {
    f32x4 o = { o0, o1, o2, o3 };
    __builtin_nontemporal_store(o, (f32x4*)((float*)out + (size_t)t * 256 + c0));
  } else {
    u16x4 o = { f2bf(o0), f2bf(o1), f2bf(o2), f2bf(o3) };
    *(u16x4*)((unsigned short*)out + (size_t)t * 256 + c0) = o;
  }
}

// ---------------- launch ----------------
extern "C" void kernel_launch(void* const* d_in, const int* in_sizes, int n_in,
                              void* d_out, int out_size, void* d_ws, size_t ws_size,
                              hipStream_t stream) {
  (void)in_sizes; (void)n_in; (void)out_size; (void)ws_size;
  const float* x   = (const float*)d_in[0];
  const float* nw  = (const float*)d_in[1];
  const int*   esrc = (const int*)d_in[2];
  const int*   etgt = (const int*)d_in[3];
  const float* Wr0 = (const float*)d_in[4];
  const float* Ws0 = (const float*)d_in[5];
  const float* Wb0 = (const float*)d_in[6];
  const float* g0  = (const float*)d_in[7];
  const float* b0  = (const float*)d_in[8];
  const float* Wr1 = (const float*)d_in[9];
  const float* Ws1 = (const float*)d_in[10];
  const float* Wb1 = (const float*)d_in[11];
  const float* g1  = (const float*)d_in[12];
  const float* b1  = (const float*)d_in[13];

  char* p = (char*)d_ws;
  auto carve = [&](size_t bytes) {
    char* q = p;
    p += (bytes + 511) & ~(size_t)511;
    return q;
  };
  unsigned short* Y   = (unsigned short*)carve((size_t)M_PAD * N_CAT * 2);  // 230.6 MB
  unsigned short* xb  = (unsigned short*)carve((size_t)M_PAD * D_IN * 2);   //  76.9 MB
  unsigned short* h   = (unsigned short*)carve((size_t)M_PAD * D_H * 2);    //  25.6 MB
  unsigned short* Wt0 = (unsigned short*)carve((size_t)N_CAT * D_IN * 2);
  unsigned short* Wt1 = (unsigned short*)carve((size_t)N_CAT * D_H * 2);
  int*   deg     = (int*)carve((size_t)R_REL * N_NODES * 4);
  int*   pdeg    = (int*)carve((size_t)N_NODES * 4);
  int*   cursor  = (int*)carve((size_t)N_NODES * 4);
  int*   nodeptr = (int*)carve((size_t)(N_NODES + 1) * 4);
  int*   bsum    = (int*)carve((size_t)NCHUNK * 4);
  int*   chunkoff= (int*)carve((size_t)NCHUNK * 4);
  int2*  e2      = (int2*)carve((size_t)E_PAD_MAX * 8);
  int2*  scN     = (int2*)carve((size_t)N_NODES * 8);

  // CSR build (node-major; shared by both layers)
  hipMemsetAsync(deg, 0, (size_t)R_REL * N_NODES * 4, stream);
  hipMemsetAsync(cursor, 0, (size_t)N_NODES * 4, stream);
  hipMemsetAsync(e2, 0, (size_t)E_PAD_MAX * 8, stream);   // pad slots -> {src0, w=0}
  k_deg<<<(R_REL * E_EDGES + 255) / 256, 256, 0, stream>>>(etgt, deg);
  k_ndeg<<<(N_NODES + 255) / 256, 256, 0, stream>>>(deg, pdeg);
  k_scan1<<<NCHUNK, 256, 0, stream>>>(pdeg, nodeptr, bsum);
  k_scan2<<<1, 64, 0, stream>>>(bsum, chunkoff, nodeptr);
  k_scan3<<<NCHUNK, 256, 0, stream>>>(chunkoff, nodeptr);
  k_prep<<<(N_NODES + 255) / 256, 256, 0, stream>>>(nodeptr, scN);
  k_fill<<<(R_REL * E_EDGES + 255) / 256, 256, 0, stream>>>(esrc, etgt, nw, nodeptr,
                                                            deg, cursor, e2);
  // conversions
  k_cvt_x<<<(N_NODES * D_IN / 4 + 255) / 256, 256, 0, stream>>>(x, xb);
  k_cvt_w<<<(N_CAT * D_IN + 255) / 256, 256, 0, stream>>>(Ws0, Wr0, Wt0, D_IN);
  k_cvt_w<<<(N_CAT * D_H + 255) / 256, 256, 0, stream>>>(Ws1, Wr1, Wt1, D_H);

  const int nblk = 8 * T_PER_XCD;   // 7040, XCD-swizzled in-kernel
  // layer 0
  k_gemm<<<nblk, 256, 0, stream>>>(xb, Wt0, Y, D_IN);
  k_gather_ln<0><<<N_NODES / 4, 256, 0, stream>>>(Y, scN, e2, Wb0, g0, b0, h);
  // layer 1
  k_gemm<<<nblk, 256, 0, stream>>>(h, Wt1, Y, D_H);
  k_gather_ln<1><<<N_NODES / 4, 256, 0, stream>>>(Y, scN, e2, Wb1, g1, b1, d_out);
}